// Round 11
// baseline (1441.823 us; speedup 1.0000x reference)
//
#include <hip/hip_runtime.h>
#include <hip/hip_bf16.h>
#include <hip/hip_cooperative_groups.h>

namespace cg = cooperative_groups;

typedef __bf16 bf16x8 __attribute__((ext_vector_type(8)));
typedef float  f32x4  __attribute__((ext_vector_type(4)));
typedef float  f32x2  __attribute__((ext_vector_type(2)));

#define BSZ 8192
#define NBLK 512    // 2 blocks/CU needed; launch_bounds allows 4 -> 2x validation margin
#define IPB  16     // images per block

// ---------------- single cooperative kernel, 7 phases ----------------
// LDS union (max phase: conv2s 26112 B)
__global__ __launch_bounds__(256, 4) void k_mega(const float* __restrict__ x,
                                                 const float* __restrict__ w0,
                                                 const float* __restrict__ g0,
                                                 const float* __restrict__ be0,
                                                 const float* __restrict__ w1,
                                                 const float* __restrict__ g1,
                                                 const float* __restrict__ be1,
                                                 const float* __restrict__ w2,
                                                 const float* __restrict__ g2,
                                                 const float* __restrict__ be2,
                                                 const float* __restrict__ wfc,
                                                 const float* __restrict__ bfc,
                                                 float* __restrict__ out,
                                                 float* __restrict__ wsf) {
    __shared__ __attribute__((aligned(16))) unsigned char smem[26112];
    cg::grid_group grid = cg::this_grid();
    const int tid = threadIdx.x, blk = blockIdx.x;

    // workspace layout
    float* part0 = wsf;                        // NBLK*64
    float* abc0  = part0 + NBLK * 64;          // 320
    float* part1 = abc0 + 320;                 // 128*NBLK
    float* abc1  = part1 + 128 * NBLK;         // 128
    float* part2 = abc1 + 128;                 // 256*NBLK
    float* abc2  = part2 + 256 * NBLK;         // 256
    __bf16* w1b  = (__bf16*)(abc2 + 256);      // 8192
    __bf16* w2b  = w1b + 8192;                 // 32768
    __bf16* h1   = w2b + 32768;                // 8192*12544

    // ================= P0: weight prep + stats0 (packed 9x9 moments) =================
    {
        float* sred = (float*)smem;            // 4*59
        for (int t = blk * 256 + tid; t < 32768; t += NBLK * 256) {
            if (t < 8192) {        // w1: 64 oc x 128 k
                int oc = t >> 7, k = t & 127, c = k & 31, d = k >> 5;
                w1b[t] = (__bf16)w1[oc * 128 + c * 4 + d];
            }
            {                      // w2: 128 oc x 256 k
                int oc = t >> 8, k = t & 255, c = k & 63, d = k >> 6;
                w2b[t] = (__bf16)w2[oc * 256 + c * 4 + d];
            }
        }
        const int base2[9] = {0, 5, 9, 13, 16, 19, 21, 23, 24};
        const int rsz[9]   = {5, 4, 4, 3, 3, 2, 2, 1, 1};
        f32x2 a2[25];
        float ax[9];
#pragma unroll
        for (int i = 0; i < 25; i++) a2[i] = (f32x2){0.f, 0.f};
#pragma unroll
        for (int i = 0; i < 9; i++) ax[i] = 0.f;
        const int total = BSZ * 784;
        for (int p = blk * 256 + tid; p < total; p += NBLK * 256) {
            int b = p / 784, pix = p - b * 784;
            int y = pix / 28, xx = pix - y * 28;
            const float* xb = x + (long)b * 784;
            float nv[9];
#pragma unroll
            for (int dy = 0; dy < 3; dy++) {
                int yy = y + dy - 1;
#pragma unroll
                for (int dx = 0; dx < 3; dx++) {
                    int x2 = xx + dx - 1;
                    nv[dy * 3 + dx] = (yy >= 0 && yy < 28 && x2 >= 0 && x2 < 28) ? xb[yy * 28 + x2] : 0.f;
                }
            }
#pragma unroll
            for (int t2 = 0; t2 < 9; t2++) {
                float vt = nv[t2];
                ax[t2] += vt;
                f32x2 vv = {vt, vt};
#pragma unroll
                for (int pp2 = 0; pp2 < 5; pp2++) {
                    if (pp2 < rsz[t2]) {
                        int u = t2 + 2 * pp2;
                        f32x2 nn = {nv[u], (u + 1 < 9) ? nv[u + 1] : 0.f};
                        a2[base2[t2] + pp2] = __builtin_elementwise_fma(vv, nn, a2[base2[t2] + pp2]);
                    }
                }
            }
        }
        float outv[59];
#pragma unroll
        for (int i = 0; i < 50; i++) outv[i] = a2[i >> 1][i & 1];
#pragma unroll
        for (int i = 0; i < 9; i++) outv[50 + i] = ax[i];
#pragma unroll
        for (int i = 0; i < 59; i++) {
            float v = outv[i];
            v += __shfl_xor(v, 1);  v += __shfl_xor(v, 2);  v += __shfl_xor(v, 4);
            v += __shfl_xor(v, 8);  v += __shfl_xor(v, 16); v += __shfl_xor(v, 32);
            outv[i] = v;
        }
        const int l = tid & 63, w = tid >> 6;
        if (l == 0) {
#pragma unroll
            for (int i = 0; i < 59; i++) sred[w * 59 + i] = outv[i];
        }
        __syncthreads();
        if (tid < 59)
            part0[blk * 64 + tid] = sred[tid] + sred[59 + tid] + sred[118 + tid] + sred[177 + tid];
    }
    grid.sync();

    // ================= P1: fin0 — fold BN0 into conv0 weights (block 0) =================
    if (blk == 0) {
        float* red = (float*)smem;             // 4*59
        int t = tid, c = t & 63, g = t >> 6;
        if (c < 59) {
            float acc = 0.f;
            for (int i = g; i < NBLK; i += 4) acc += part0[i * 64 + c];
            red[g * 59 + c] = acc;
        }
        __syncthreads();
        if (t < 59) red[t] = red[t] + red[59 + t] + red[118 + t] + red[177 + t];
        __syncthreads();
        if (t < 32) {
            const int base2[9] = {0, 5, 9, 13, 16, 19, 21, 23, 24};
            float wv[9];
#pragma unroll
            for (int tap = 0; tap < 9; tap++) wv[tap] = w0[t * 9 + tap];
            float sum = 0.f, sq = 0.f;
#pragma unroll
            for (int ta = 0; ta < 9; ta++) {
                sum = fmaf(wv[ta], red[50 + ta], sum);
#pragma unroll
                for (int u = ta; u < 9; u++) {
                    float coef = (u == ta) ? 1.f : 2.f;
                    float Mv = red[2 * base2[ta] + (u - ta)];
                    sq = fmaf(coef * wv[ta] * wv[u], Mv, sq);
                }
            }
            float cnt = (float)BSZ * 784.f;
            float mean = sum / cnt;
            float var = sq / cnt - mean * mean;
            float A = g0[t] * rsqrtf(var + 1e-5f);
#pragma unroll
            for (int tap = 0; tap < 9; tap++)
                abc0[(t >> 3) * 72 + tap * 8 + (t & 7)] = A * wv[tap];
            abc0[288 + t] = be0[t] - mean * A;
        }
    }
    grid.sync();

    // ================= P2: conv0(+BN0 folded, packed)+ReLU + MFMA conv1 (IPB img) =================
    {
        float* xs = (float*)smem;                         // 900 floats
        __bf16* sAt = (__bf16*)(smem + 3600);             // [2][16*136]
        if (tid < 116) {
            int idx;
            if (tid < 30)      idx = tid;
            else if (tid < 60) idx = 29 * 30 + (tid - 30);
            else if (tid < 88) idx = (tid - 60 + 1) * 30;
            else               idx = (tid - 88 + 1) * 30 + 29;
            xs[idx] = 0.f;
        }
        const int pgu = __builtin_amdgcn_readfirstlane(tid >> 6);
        const f32x2* wfp = (const f32x2*)(abc0 + pgu * 72);
        f32x2 wf2[36];
#pragma unroll
        for (int i = 0; i < 36; i++) wf2[i] = wfp[i];
        const f32x2* c2p = (const f32x2*)(abc0 + 288 + pgu * 8);
        f32x2 c2[4];
#pragma unroll
        for (int j = 0; j < 4; j++) c2[j] = c2p[j];
        const int pi = tid & 15, pd = (tid >> 4) & 3;
        const int w = tid >> 6, l = tid & 63, q = l >> 4, n = l & 15;
        const int oc = w * 16 + n;
        bf16x8 fbv[4];
#pragma unroll
        for (int kc = 0; kc < 4; kc++)
            fbv[kc] = *(const bf16x8*)&w1b[oc * 128 + kc * 32 + q * 8];
        const f32x2 zero2 = {0.f, 0.f};
        f32x2 st_s = zero2, st_q = zero2;   // accumulate across IPB images

        for (int img = 0; img < IPB; img++) {
            const int b = blk * IPB + img;
            const f32x4* xb4 = (const f32x4*)(x + (long)b * 784);
            if (tid < 196) {
                int yy = tid / 7, xx4 = (tid - yy * 7) * 4;
                f32x4 v4 = xb4[tid];
                float* dst = &xs[(yy + 1) * 30 + xx4 + 1];
                dst[0] = v4[0]; dst[1] = v4[1]; dst[2] = v4[2]; dst[3] = v4[3];
            }
            __syncthreads();   // xs ready; epoch-separates sAt reuse
            __bf16* hb = h1 + (long)b * 12544 + (q * 4) * 64 + oc;
            for (int mt = 0; mt < 13; mt++) {
                __bf16* dst = &sAt[(mt & 1) * 2176 + pi * 136 + pd * 32 + pgu * 8];
                int m = mt * 16 + pi;
                bf16x8 pk;
                if (m < 196) {
                    int my = m / 14, mx = m - my * 14;
                    int y0 = my * 2 + (pd >> 1), x0 = mx * 2 + (pd & 1);
                    float nv[9];
#pragma unroll
                    for (int dy = 0; dy < 3; dy++)
#pragma unroll
                        for (int dx = 0; dx < 3; dx++)
                            nv[dy * 3 + dx] = xs[(y0 + dy) * 30 + x0 + dx];
                    f32x2 a2[4];
#pragma unroll
                    for (int j = 0; j < 4; j++) a2[j] = c2[j];
#pragma unroll
                    for (int t = 0; t < 9; t++) {
                        f32x2 vv = {nv[t], nv[t]};
#pragma unroll
                        for (int j = 0; j < 4; j++)
                            a2[j] = __builtin_elementwise_fma(vv, wf2[t * 4 + j], a2[j]);
                    }
#pragma unroll
                    for (int j = 0; j < 4; j++) {
                        f32x2 mv = __builtin_elementwise_max(a2[j], zero2);
                        pk[2 * j]     = (__bf16)mv[0];
                        pk[2 * j + 1] = (__bf16)mv[1];
                    }
                } else {
#pragma unroll
                    for (int j = 0; j < 8; j++) pk[j] = (__bf16)0.0f;
                }
                *(bf16x8*)dst = pk;
                __syncthreads();
                const __bf16* sa = &sAt[(mt & 1) * 2176 + n * 136 + q * 8];
                f32x4 acc = {0.f, 0.f, 0.f, 0.f};
#pragma unroll
                for (int kc = 0; kc < 4; kc++) {
                    bf16x8 fav = *(const bf16x8*)&sa[kc * 32];
                    acc = __builtin_amdgcn_mfma_f32_16x16x32_bf16(fav, fbv[kc], acc, 0, 0, 0);
                }
                bool valid = (mt < 12) | (q == 0);
                __bf16* hp = hb + mt * 16 * 64;
                float fv[4];
#pragma unroll
                for (int r = 0; r < 4; r++) {
                    __bf16 hv = (__bf16)acc[r];
                    if (valid) hp[r * 64] = hv;
                    fv[r] = (float)hv;              // padded rows -> 0
                }
                f32x2 f01 = {fv[0], fv[1]}, f23 = {fv[2], fv[3]};
                st_s = st_s + f01; st_s = st_s + f23;
                st_q = __builtin_elementwise_fma(f01, f01, st_q);
                st_q = __builtin_elementwise_fma(f23, f23, st_q);
            }
            __syncthreads();   // consumers done before next image's xs/sAt overwrite
        }
        float ssum = st_s[0] + st_s[1], ssq = st_q[0] + st_q[1];
        ssum += __shfl_xor(ssum, 16); ssum += __shfl_xor(ssum, 32);
        ssq  += __shfl_xor(ssq, 16);  ssq  += __shfl_xor(ssq, 32);
        if (l < 16) {
            part1[(long)oc * NBLK + blk] = ssum;
            part1[(long)(64 + oc) * NBLK + blk] = ssq;
        }
    }
    grid.sync();

    // ================= P3: redfin1 (blocks 0..63) =================
    if (blk < 64) {
        float* s1 = (float*)smem;
        float* s2 = (float*)(smem + 1024);
        const int c = blk;
        float a = 0.f, bq = 0.f;
        const float* p1 = part1 + (long)c * NBLK;
        const float* p2 = part1 + (long)(64 + c) * NBLK;
        for (int i = tid; i < NBLK; i += 256) { a += p1[i]; bq += p2[i]; }
        s1[tid] = a; s2[tid] = bq;
        __syncthreads();
        for (int s = 128; s > 0; s >>= 1) {
            if (tid < s) { s1[tid] += s1[tid + s]; s2[tid] += s2[tid + s]; }
            __syncthreads();
        }
        if (tid == 0) {
            float cnt = (float)(BSZ * 196);
            float mean = s1[0] / cnt;
            float var = s2[0] / cnt - mean * mean;
            float A = g1[c] * rsqrtf(var + 1e-5f);
            abc1[c] = A;
            abc1[64 + c] = be1[c] - mean * A;
        }
    }
    grid.sync();

    // ================= P4: conv2 MFMA (BN1+ReLU packed), dbuf zt (IPB img) =================
    {
        __bf16* sAt = (__bf16*)smem;                      // [2][16*264] = 16896 B
        __bf16* zt  = (__bf16*)(smem + 16896);            // [2][16*136] = 8704 B
        float* sbn1 = (float*)(smem + 25600);             // 128 floats
        if (tid < 128) sbn1[tid] = abc1[tid];
        const int w = tid >> 6, l = tid & 63, q = l >> 4, n = l & 15;
        bf16x8 fbv[2][8];
#pragma unroll
        for (int ntl = 0; ntl < 2; ntl++) {
            int oc = (2 * w + ntl) * 16 + n;
#pragma unroll
            for (int kc = 0; kc < 8; kc++)
                fbv[ntl][kc] = *(const bf16x8*)&w2b[oc * 256 + kc * 32 + q * 8];
        }
        __syncthreads();   // sbn1 ready
        const int cpb = (tid & 7) * 8;
        f32x2 A1p[4], C1p[4];
#pragma unroll
        for (int p = 0; p < 4; p++) {
            A1p[p] = (f32x2){sbn1[cpb + 2 * p], sbn1[cpb + 2 * p + 1]};
            C1p[p] = (f32x2){sbn1[64 + cpb + 2 * p], sbn1[64 + cpb + 2 * p + 1]};
        }
        const f32x2 zero2 = {0.f, 0.f};
        const int srow = tid >> 4, so = (tid & 15) * 8;
        f32x2 st_s[2] = {zero2, zero2}, st_q[2] = {zero2, zero2};

        for (int img = 0; img < IPB; img++) {
            const int b = blk * IPB + img;
            __bf16* src = h1 + (long)b * 12544;
            for (int mt = 0; mt < 4; mt++) {
                if (mt >= 2) {
                    int m = (mt - 2) * 16 + srow;
                    if (m < 49) {
                        bf16x8 zv = *(const bf16x8*)&zt[(mt & 1) * 2176 + srow * 136 + so];
                        *(bf16x8*)&src[m * 128 + so] = zv;
                    }
                }
#pragma unroll
                for (int it = 0; it < 2; it++) {
                    int idx = it * 256 + tid;
                    int rl = idx >> 5, o = (idx & 31) * 8;
                    int r = mt * 16 + rl;
                    bf16x8 wv;
                    if (r < 49) {
                        int d = o >> 6;
                        int c = o & 63;
                        int py = r / 7, px = r - py * 7;
                        int msrc = (2 * py + (d >> 1)) * 14 + 2 * px + (d & 1);
                        bf16x8 v = *(const bf16x8*)&src[msrc * 64 + c];
#pragma unroll
                        for (int p = 0; p < 4; p++) {
                            f32x2 vf = {(float)v[2 * p], (float)v[2 * p + 1]};
                            f32x2 rr = __builtin_elementwise_fma(vf, A1p[p], C1p[p]);
                            rr = __builtin_elementwise_max(rr, zero2);
                            wv[2 * p]     = (__bf16)rr[0];
                            wv[2 * p + 1] = (__bf16)rr[1];
                        }
                    } else {
#pragma unroll
                        for (int j = 0; j < 8; j++) wv[j] = (__bf16)0.0f;
                    }
                    *(bf16x8*)&sAt[(mt & 1) * 4224 + rl * 264 + o] = wv;
                }
                __syncthreads();
                bf16x8 fav[8];
#pragma unroll
                for (int kc = 0; kc < 8; kc++)
                    fav[kc] = *(const bf16x8*)&sAt[(mt & 1) * 4224 + n * 264 + kc * 32 + q * 8];
#pragma unroll
                for (int ntl = 0; ntl < 2; ntl++) {
                    f32x4 acc = {0.f, 0.f, 0.f, 0.f};
#pragma unroll
                    for (int kc = 0; kc < 8; kc++)
                        acc = __builtin_amdgcn_mfma_f32_16x16x32_bf16(fav[kc], fbv[ntl][kc], acc, 0, 0, 0);
                    float fv[4];
#pragma unroll
                    for (int rr = 0; rr < 4; rr++) {
                        __bf16 hv = (__bf16)acc[rr];
                        zt[(mt & 1) * 2176 + (q * 4 + rr) * 136 + (2 * w + ntl) * 16 + n] = hv;
                        fv[rr] = (float)hv;
                    }
                    f32x2 f01 = {fv[0], fv[1]}, f23 = {fv[2], fv[3]};
                    st_s[ntl] = st_s[ntl] + f01; st_s[ntl] = st_s[ntl] + f23;
                    st_q[ntl] = __builtin_elementwise_fma(f01, f01, st_q[ntl]);
                    st_q[ntl] = __builtin_elementwise_fma(f23, f23, st_q[ntl]);
                }
            }
            __syncthreads();
            // drain tiles 2 (zt[0]) and 3 (zt[1])
            {
                int m2 = 32 + srow;
                if (m2 < 49) {
                    bf16x8 zv = *(const bf16x8*)&zt[srow * 136 + so];
                    *(bf16x8*)&src[m2 * 128 + so] = zv;
                }
                int m3 = 48 + srow;
                if (m3 < 49) {
                    bf16x8 zv = *(const bf16x8*)&zt[2176 + srow * 136 + so];
                    *(bf16x8*)&src[m3 * 128 + so] = zv;
                }
            }
        }
#pragma unroll
        for (int ntl = 0; ntl < 2; ntl++) {
            float ssum = st_s[ntl][0] + st_s[ntl][1];
            float ssq  = st_q[ntl][0] + st_q[ntl][1];
            ssum += __shfl_xor(ssum, 16); ssum += __shfl_xor(ssum, 32);
            ssq  += __shfl_xor(ssq, 16);  ssq  += __shfl_xor(ssq, 32);
            if (l < 16) {
                int oc = (2 * w + ntl) * 16 + l;
                part2[(long)oc * NBLK + blk] = ssum;
                part2[(long)(128 + oc) * NBLK + blk] = ssq;
            }
        }
    }
    grid.sync();

    // ================= P5: redfin2 (blocks 0..127) =================
    if (blk < 128) {
        float* s1 = (float*)smem;
        float* s2 = (float*)(smem + 1024);
        const int c = blk;
        float a = 0.f, bq = 0.f;
        const float* p1 = part2 + (long)c * NBLK;
        const float* p2 = part2 + (long)(128 + c) * NBLK;
        for (int i = tid; i < NBLK; i += 256) { a += p1[i]; bq += p2[i]; }
        s1[tid] = a; s2[tid] = bq;
        __syncthreads();
        for (int s = 128; s > 0; s >>= 1) {
            if (tid < s) { s1[tid] += s1[tid + s]; s2[tid] += s2[tid + s]; }
            __syncthreads();
        }
        if (tid == 0) {
            float cnt = (float)(BSZ * 49);
            float mean = s1[0] / cnt;
            float var = s2[0] / cnt - mean * mean;
            float A = g2[c] * rsqrtf(var + 1e-5f);
            abc2[c] = A;
            abc2[128 + c] = be2[c] - mean * A;
        }
    }
    grid.sync();

    // ================= P6: BN2(packed)+ReLU+avgpool+FC (IPB img) =================
    {
        float* sbn2 = (float*)smem;               // 256
        float* pp   = (float*)(smem + 1024);      // 16*128
        float* pooled = (float*)(smem + 9216);    // 128
        float* fcred  = (float*)(smem + 9728);    // 80
        sbn2[tid] = abc2[tid];
        __syncthreads();
        const int g = tid & 15, c0 = g * 8, rg = tid >> 4;
        f32x2 A2p[4], C2p[4];
#pragma unroll
        for (int p = 0; p < 4; p++) {
            A2p[p] = (f32x2){sbn2[c0 + 2 * p], sbn2[c0 + 2 * p + 1]};
            C2p[p] = (f32x2){sbn2[128 + c0 + 2 * p], sbn2[128 + c0 + 2 * p + 1]};
        }
        const f32x2 zero2 = {0.f, 0.f};
        for (int img = 0; img < IPB; img++) {
            const int b = blk * IPB + img;
            const __bf16* src = h1 + (long)b * 12544;
            f32x2 acc2[4];
#pragma unroll
            for (int p = 0; p < 4; p++) acc2[p] = zero2;
            for (int rr = rg; rr < 49; rr += 16) {
                bf16x8 v = *(const bf16x8*)&src[rr * 128 + c0];
#pragma unroll
                for (int p = 0; p < 4; p++) {
                    f32x2 vf = {(float)v[2 * p], (float)v[2 * p + 1]};
                    f32x2 t0 = __builtin_elementwise_fma(vf, A2p[p], C2p[p]);
                    t0 = __builtin_elementwise_max(t0, zero2);
                    acc2[p] = acc2[p] + t0;
                }
            }
            f32x4 lo = {acc2[0][0], acc2[0][1], acc2[1][0], acc2[1][1]};
            f32x4 hi = {acc2[2][0], acc2[2][1], acc2[3][0], acc2[3][1]};
            *(f32x4*)&pp[rg * 128 + c0]     = lo;
            *(f32x4*)&pp[rg * 128 + c0 + 4] = hi;
            __syncthreads();
            if (tid < 128) {
                float s = 0.f;
#pragma unroll
                for (int r = 0; r < 16; r++) s += pp[r * 128 + tid];
                pooled[tid] = s * (1.f / 49.f);
            }
            __syncthreads();
            if (tid < 80) {
                int o = tid >> 3, s = tid & 7;
                float a = 0.f;
#pragma unroll
                for (int j = 0; j < 16; j++) a = fmaf(pooled[s * 16 + j], wfc[o * 128 + s * 16 + j], a);
                fcred[tid] = a;
            }
            __syncthreads();
            if (tid < 10) {
                float a = bfc[tid];
#pragma unroll
                for (int s = 0; s < 8; s++) a += fcred[tid * 8 + s];
                out[(long)b * 10 + tid] = a;
            }
            __syncthreads();   // fcred/pooled reuse next image
        }
    }
}

extern "C" void kernel_launch(void* const* d_in, const int* in_sizes, int n_in,
                              void* d_out, int out_size, void* d_ws, size_t ws_size,
                              hipStream_t stream) {
    const float* x   = (const float*)d_in[0];
    const float* w0  = (const float*)d_in[1];
    const float* g0  = (const float*)d_in[3];
    const float* be0 = (const float*)d_in[4];
    const float* w1  = (const float*)d_in[5];
    const float* g1  = (const float*)d_in[7];
    const float* be1 = (const float*)d_in[8];
    const float* w2  = (const float*)d_in[9];
    const float* g2  = (const float*)d_in[11];
    const float* be2 = (const float*)d_in[12];
    const float* wfc = (const float*)d_in[13];
    const float* bfc = (const float*)d_in[14];
    float* out = (float*)d_out;
    float* wsf = (float*)d_ws;

    void* args[] = {(void*)&x, (void*)&w0, (void*)&g0, (void*)&be0,
                    (void*)&w1, (void*)&g1, (void*)&be1,
                    (void*)&w2, (void*)&g2, (void*)&be2,
                    (void*)&wfc, (void*)&bfc, (void*)&out, (void*)&wsf};
    hipLaunchCooperativeKernel((void*)k_mega, dim3(NBLK), dim3(256), args, 0, stream);
}

// Round 12
// 895.021 us; speedup vs baseline: 1.6109x; 1.6109x over previous
//
#include <hip/hip_runtime.h>
#include <hip/hip_bf16.h>

typedef __bf16 bf16x8 __attribute__((ext_vector_type(8)));
typedef float  f32x4  __attribute__((ext_vector_type(4)));
typedef float  f32x2  __attribute__((ext_vector_type(2)));

#define BSZ 8192

// ws control layout (floats): [0..63] acc0 (59 used), [64..191] acc1, [192..447] acc2,
// [448] ticket0, [449] ticket1, [450] ticket2. Zeroed via hipMemsetAsync (2048 B).

// ---------------- stats0 (packed 9x9 moments) + weight prep + last-block fin0 ----------------
__global__ __launch_bounds__(256) void k_stats0(const float* __restrict__ x,
                                                float* __restrict__ ctrl,
                                                const float* __restrict__ w0,
                                                const float* __restrict__ g0,
                                                const float* __restrict__ be0,
                                                float* __restrict__ abc0,
                                                const float* __restrict__ w1,
                                                const float* __restrict__ w2,
                                                __bf16* __restrict__ w1b,
                                                __bf16* __restrict__ w2b) {
    __shared__ float sred[4 * 59];
    __shared__ int slast;
    const int tid = threadIdx.x, blk = blockIdx.x;
    {   // merged weight prep (grid 1024 x 256 covers 32768)
        int t = blk * 256 + tid;
        if (t < 8192) {            // w1: 64 oc x 128 k
            int oc = t >> 7, k = t & 127, c = k & 31, d = k >> 5;
            w1b[t] = (__bf16)w1[oc * 128 + c * 4 + d];
        }
        if (t < 32768) {           // w2: 128 oc x 256 k
            int oc = t >> 8, k = t & 255, c = k & 63, d = k >> 6;
            w2b[t] = (__bf16)w2[oc * 256 + c * 4 + d];
        }
    }
    const int base2[9] = {0, 5, 9, 13, 16, 19, 21, 23, 24};
    const int rsz[9]   = {5, 4, 4, 3, 3, 2, 2, 1, 1};
    f32x2 a2[25];
    float ax[9];
#pragma unroll
    for (int i = 0; i < 25; i++) a2[i] = (f32x2){0.f, 0.f};
#pragma unroll
    for (int i = 0; i < 9; i++) ax[i] = 0.f;
    const int total = BSZ * 784;
    for (int p = blk * 256 + tid; p < total; p += gridDim.x * 256) {
        int b = p / 784, pix = p - b * 784;
        int y = pix / 28, xx = pix - y * 28;
        const float* xb = x + (long)b * 784;
        float nv[9];
#pragma unroll
        for (int dy = 0; dy < 3; dy++) {
            int yy = y + dy - 1;
#pragma unroll
            for (int dx = 0; dx < 3; dx++) {
                int x2 = xx + dx - 1;
                nv[dy * 3 + dx] = (yy >= 0 && yy < 28 && x2 >= 0 && x2 < 28) ? xb[yy * 28 + x2] : 0.f;
            }
        }
#pragma unroll
        for (int t2 = 0; t2 < 9; t2++) {
            float vt = nv[t2];
            ax[t2] += vt;
            f32x2 vv = {vt, vt};
#pragma unroll
            for (int pp2 = 0; pp2 < 5; pp2++) {
                if (pp2 < rsz[t2]) {
                    int u = t2 + 2 * pp2;
                    f32x2 nn = {nv[u], (u + 1 < 9) ? nv[u + 1] : 0.f};
                    a2[base2[t2] + pp2] = __builtin_elementwise_fma(vv, nn, a2[base2[t2] + pp2]);
                }
            }
        }
    }
    float outv[59];
#pragma unroll
    for (int i = 0; i < 50; i++) outv[i] = a2[i >> 1][i & 1];
#pragma unroll
    for (int i = 0; i < 9; i++) outv[50 + i] = ax[i];
#pragma unroll
    for (int i = 0; i < 59; i++) {
        float v = outv[i];
        v += __shfl_xor(v, 1);  v += __shfl_xor(v, 2);  v += __shfl_xor(v, 4);
        v += __shfl_xor(v, 8);  v += __shfl_xor(v, 16); v += __shfl_xor(v, 32);
        outv[i] = v;
    }
    const int l = tid & 63, w = tid >> 6;
    if (l == 0) {
#pragma unroll
        for (int i = 0; i < 59; i++) sred[w * 59 + i] = outv[i];
    }
    __syncthreads();
    if (tid < 59)
        atomicAdd(&ctrl[tid], sred[tid] + sred[59 + tid] + sred[118 + tid] + sred[177 + tid]);
    // last-block fin0
    __threadfence();
    if (tid == 0) {
        int old = atomicAdd((int*)&ctrl[448], 1);
        slast = (old == (int)gridDim.x - 1) ? 1 : 0;
    }
    __syncthreads();
    if (slast) {
        __threadfence();
        __shared__ float red[59];
        if (tid < 59) red[tid] = atomicAdd(&ctrl[tid], 0.f);
        __syncthreads();
        if (tid < 32) {
            float wv[9];
#pragma unroll
            for (int tap = 0; tap < 9; tap++) wv[tap] = w0[tid * 9 + tap];
            float sum = 0.f, sq = 0.f;
#pragma unroll
            for (int ta = 0; ta < 9; ta++) {
                sum = fmaf(wv[ta], red[50 + ta], sum);
#pragma unroll
                for (int u = ta; u < 9; u++) {
                    float coef = (u == ta) ? 1.f : 2.f;
                    float Mv = red[2 * base2[ta] + (u - ta)];
                    sq = fmaf(coef * wv[ta] * wv[u], Mv, sq);
                }
            }
            float cnt = (float)BSZ * 784.f;
            float mean = sum / cnt;
            float var = sq / cnt - mean * mean;
            float A = g0[tid] * rsqrtf(var + 1e-5f);
#pragma unroll
            for (int tap = 0; tap < 9; tap++)
                abc0[(tid >> 3) * 72 + tap * 8 + (tid & 7)] = A * wv[tap];
            abc0[288 + tid] = be0[tid] - mean * A;
        }
    }
}

// ---------------- conv0(+BN0 folded, packed)+ReLU + MFMA conv1 (IPB=4) + last-block BN1 finalize ----------------
__global__ __launch_bounds__(256) void k_conv01(const float* __restrict__ x,
                                                const float* __restrict__ abc0,
                                                const __bf16* __restrict__ w1b,
                                                __bf16* __restrict__ h1,
                                                float* __restrict__ ctrl,
                                                const float* __restrict__ g1,
                                                const float* __restrict__ be1,
                                                float* __restrict__ abc1) {
    __shared__ float xs[30 * 30];
    __shared__ __attribute__((aligned(16))) __bf16 sAt[2][16 * 136];
    __shared__ int slast;
    const int tid = threadIdx.x;
    if (tid < 116) {
        int idx;
        if (tid < 30)      idx = tid;
        else if (tid < 60) idx = 29 * 30 + (tid - 30);
        else if (tid < 88) idx = (tid - 60 + 1) * 30;
        else               idx = (tid - 88 + 1) * 30 + 29;
        xs[idx] = 0.f;
    }
    const int pgu = __builtin_amdgcn_readfirstlane(tid >> 6);
    const f32x2* wfp = (const f32x2*)(abc0 + pgu * 72);
    f32x2 wf2[36];
#pragma unroll
    for (int i = 0; i < 36; i++) wf2[i] = wfp[i];
    const f32x2* c2p = (const f32x2*)(abc0 + 288 + pgu * 8);
    f32x2 c2[4];
#pragma unroll
    for (int j = 0; j < 4; j++) c2[j] = c2p[j];

    const int pi = tid & 15, pd = (tid >> 4) & 3;
    const int w = tid >> 6, l = tid & 63, q = l >> 4, n = l & 15;
    const int oc = w * 16 + n;
    bf16x8 fbv[4];
#pragma unroll
    for (int kc = 0; kc < 4; kc++)
        fbv[kc] = *(const bf16x8*)&w1b[oc * 128 + kc * 32 + q * 8];
    const f32x2 zero2 = {0.f, 0.f};
    f32x2 st_s = zero2, st_q = zero2;    // accumulated across all 4 images

    for (int img = 0; img < 4; img++) {
        const int b = blockIdx.x * 4 + img;
        const f32x4* xb4 = (const f32x4*)(x + (long)b * 784);
        if (tid < 196) {
            int yy = tid / 7, xx4 = (tid - yy * 7) * 4;
            f32x4 v4 = xb4[tid];
            float* dst = &xs[(yy + 1) * 30 + xx4 + 1];
            dst[0] = v4[0]; dst[1] = v4[1]; dst[2] = v4[2]; dst[3] = v4[3];
        }
        __syncthreads();
        __bf16* hb = h1 + (long)b * 12544 + (q * 4) * 64 + oc;
        for (int mt = 0; mt < 13; mt++) {
            __bf16* dst = &sAt[mt & 1][pi * 136 + pd * 32 + pgu * 8];
            int m = mt * 16 + pi;
            bf16x8 pk;
            if (m < 196) {
                int my = m / 14, mx = m - my * 14;
                int y0 = my * 2 + (pd >> 1), x0 = mx * 2 + (pd & 1);
                float nv[9];
#pragma unroll
                for (int dy = 0; dy < 3; dy++)
#pragma unroll
                    for (int dx = 0; dx < 3; dx++)
                        nv[dy * 3 + dx] = xs[(y0 + dy) * 30 + x0 + dx];
                f32x2 a2[4];
#pragma unroll
                for (int j = 0; j < 4; j++) a2[j] = c2[j];
#pragma unroll
                for (int t = 0; t < 9; t++) {
                    f32x2 vv = {nv[t], nv[t]};
#pragma unroll
                    for (int j = 0; j < 4; j++)
                        a2[j] = __builtin_elementwise_fma(vv, wf2[t * 4 + j], a2[j]);
                }
#pragma unroll
                for (int j = 0; j < 4; j++) {
                    f32x2 mv = __builtin_elementwise_max(a2[j], zero2);
                    pk[2 * j]     = (__bf16)mv[0];
                    pk[2 * j + 1] = (__bf16)mv[1];
                }
            } else {
#pragma unroll
                for (int j = 0; j < 8; j++) pk[j] = (__bf16)0.0f;
            }
            *(bf16x8*)dst = pk;
            __syncthreads();
            const __bf16* sa = &sAt[mt & 1][n * 136 + q * 8];
            f32x4 acc = {0.f, 0.f, 0.f, 0.f};
#pragma unroll
            for (int kc = 0; kc < 4; kc++) {
                bf16x8 fav = *(const bf16x8*)&sa[kc * 32];
                acc = __builtin_amdgcn_mfma_f32_16x16x32_bf16(fav, fbv[kc], acc, 0, 0, 0);
            }
            bool valid = (mt < 12) | (q == 0);
            __bf16* hp = hb + mt * 16 * 64;
            float fv[4];
#pragma unroll
            for (int r = 0; r < 4; r++) {
                __bf16 hv = (__bf16)acc[r];
                if (valid) hp[r * 64] = hv;
                fv[r] = (float)hv;               // padded rows -> 0
            }
            f32x2 f01 = {fv[0], fv[1]}, f23 = {fv[2], fv[3]};
            st_s = st_s + f01; st_s = st_s + f23;
            st_q = __builtin_elementwise_fma(f01, f01, st_q);
            st_q = __builtin_elementwise_fma(f23, f23, st_q);
        }
        __syncthreads();   // consumers done before next image's xs/sAt overwrite
    }
    float ssum = st_s[0] + st_s[1], ssq = st_q[0] + st_q[1];
    ssum += __shfl_xor(ssum, 16); ssum += __shfl_xor(ssum, 32);
    ssq  += __shfl_xor(ssq, 16);  ssq  += __shfl_xor(ssq, 32);
    if (l < 16) {
        atomicAdd(&ctrl[64 + oc], ssum);
        atomicAdd(&ctrl[64 + 64 + oc], ssq);
    }
    // last-block BN1 finalize
    __threadfence();
    if (tid == 0) {
        int old = atomicAdd((int*)&ctrl[449], 1);
        slast = (old == (int)gridDim.x - 1) ? 1 : 0;
    }
    __syncthreads();
    if (slast) {
        __threadfence();
        if (tid < 64) {
            float sum = atomicAdd(&ctrl[64 + tid], 0.f);
            float sq  = atomicAdd(&ctrl[128 + tid], 0.f);
            float cnt = (float)(BSZ * 196);
            float mean = sum / cnt;
            float var = sq / cnt - mean * mean;
            float A = g1[tid] * rsqrtf(var + 1e-5f);
            abc1[tid] = A;
            abc1[64 + tid] = be1[tid] - mean * A;
        }
    }
}

// ---------------- conv2 MFMA (BN1+ReLU packed), dbuf zt (IPB=4) + last-block BN2 finalize ----------------
__global__ __launch_bounds__(256) void k_conv2s(__bf16* __restrict__ h1,
                                                const __bf16* __restrict__ w2b,
                                                const float* __restrict__ abc1,
                                                float* __restrict__ ctrl,
                                                const float* __restrict__ g2,
                                                const float* __restrict__ be2,
                                                float* __restrict__ abc2) {
    __shared__ __attribute__((aligned(16))) __bf16 sAt[2][16 * 264];
    __shared__ __attribute__((aligned(16))) __bf16 zt[2][16 * 136];
    __shared__ float sbn1[128];
    __shared__ int slast;
    const int tid = threadIdx.x;
    if (tid < 128) sbn1[tid] = abc1[tid];
    const int w = tid >> 6, l = tid & 63, q = l >> 4, n = l & 15;
    bf16x8 fbv[2][8];
#pragma unroll
    for (int ntl = 0; ntl < 2; ntl++) {
        int oc = (2 * w + ntl) * 16 + n;
#pragma unroll
        for (int kc = 0; kc < 8; kc++)
            fbv[ntl][kc] = *(const bf16x8*)&w2b[oc * 256 + kc * 32 + q * 8];
    }
    __syncthreads();
    const int cpb = (tid & 7) * 8;
    f32x2 A1p[4], C1p[4];
#pragma unroll
    for (int p = 0; p < 4; p++) {
        A1p[p] = (f32x2){sbn1[cpb + 2 * p], sbn1[cpb + 2 * p + 1]};
        C1p[p] = (f32x2){sbn1[64 + cpb + 2 * p], sbn1[64 + cpb + 2 * p + 1]};
    }
    const f32x2 zero2 = {0.f, 0.f};
    const int srow = tid >> 4, so = (tid & 15) * 8;
    f32x2 st_s[2] = {zero2, zero2}, st_q[2] = {zero2, zero2};

    for (int img = 0; img < 4; img++) {
        const int b = blockIdx.x * 4 + img;
        __bf16* src = h1 + (long)b * 12544;
        for (int mt = 0; mt < 4; mt++) {
            if (mt >= 2) {
                int m = (mt - 2) * 16 + srow;
                if (m < 49) {
                    bf16x8 zv = *(const bf16x8*)&zt[mt & 1][srow * 136 + so];
                    *(bf16x8*)&src[m * 128 + so] = zv;
                }
            }
#pragma unroll
            for (int it = 0; it < 2; it++) {
                int idx = it * 256 + tid;
                int rl = idx >> 5, o = (idx & 31) * 8;
                int r = mt * 16 + rl;
                bf16x8 wv;
                if (r < 49) {
                    int d = o >> 6;
                    int c = o & 63;
                    int py = r / 7, px = r - py * 7;
                    int msrc = (2 * py + (d >> 1)) * 14 + 2 * px + (d & 1);
                    bf16x8 v = *(const bf16x8*)&src[msrc * 64 + c];
#pragma unroll
                    for (int p = 0; p < 4; p++) {
                        f32x2 vf = {(float)v[2 * p], (float)v[2 * p + 1]};
                        f32x2 rr = __builtin_elementwise_fma(vf, A1p[p], C1p[p]);
                        rr = __builtin_elementwise_max(rr, zero2);
                        wv[2 * p]     = (__bf16)rr[0];
                        wv[2 * p + 1] = (__bf16)rr[1];
                    }
                } else {
#pragma unroll
                    for (int j = 0; j < 8; j++) wv[j] = (__bf16)0.0f;
                }
                *(bf16x8*)&sAt[mt & 1][rl * 264 + o] = wv;
            }
            __syncthreads();
            bf16x8 fav[8];
#pragma unroll
            for (int kc = 0; kc < 8; kc++)
                fav[kc] = *(const bf16x8*)&sAt[mt & 1][n * 264 + kc * 32 + q * 8];
#pragma unroll
            for (int ntl = 0; ntl < 2; ntl++) {
                f32x4 acc = {0.f, 0.f, 0.f, 0.f};
#pragma unroll
                for (int kc = 0; kc < 8; kc++)
                    acc = __builtin_amdgcn_mfma_f32_16x16x32_bf16(fav[kc], fbv[ntl][kc], acc, 0, 0, 0);
                float fv[4];
#pragma unroll
                for (int rr = 0; rr < 4; rr++) {
                    __bf16 hv = (__bf16)acc[rr];
                    zt[mt & 1][(q * 4 + rr) * 136 + (2 * w + ntl) * 16 + n] = hv;
                    fv[rr] = (float)hv;
                }
                f32x2 f01 = {fv[0], fv[1]}, f23 = {fv[2], fv[3]};
                st_s[ntl] = st_s[ntl] + f01; st_s[ntl] = st_s[ntl] + f23;
                st_q[ntl] = __builtin_elementwise_fma(f01, f01, st_q[ntl]);
                st_q[ntl] = __builtin_elementwise_fma(f23, f23, st_q[ntl]);
            }
        }
        __syncthreads();
        // drain tiles 2 (zt[0]) and 3 (zt[1])
        {
            int m2 = 32 + srow;
            if (m2 < 49) {
                bf16x8 zv = *(const bf16x8*)&zt[0][srow * 136 + so];
                *(bf16x8*)&src[m2 * 128 + so] = zv;
            }
            int m3 = 48 + srow;
            if (m3 < 49) {
                bf16x8 zv = *(const bf16x8*)&zt[1][srow * 136 + so];
                *(bf16x8*)&src[m3 * 128 + so] = zv;
            }
        }
    }
#pragma unroll
    for (int ntl = 0; ntl < 2; ntl++) {
        float ssum = st_s[ntl][0] + st_s[ntl][1];
        float ssq  = st_q[ntl][0] + st_q[ntl][1];
        ssum += __shfl_xor(ssum, 16); ssum += __shfl_xor(ssum, 32);
        ssq  += __shfl_xor(ssq, 16);  ssq  += __shfl_xor(ssq, 32);
        if (l < 16) {
            int oc = (2 * w + ntl) * 16 + l;
            atomicAdd(&ctrl[192 + oc], ssum);
            atomicAdd(&ctrl[192 + 128 + oc], ssq);
        }
    }
    // last-block BN2 finalize
    __threadfence();
    if (tid == 0) {
        int old = atomicAdd((int*)&ctrl[450], 1);
        slast = (old == (int)gridDim.x - 1) ? 1 : 0;
    }
    __syncthreads();
    if (slast) {
        __threadfence();
        if (tid < 128) {
            float sum = atomicAdd(&ctrl[192 + tid], 0.f);
            float sq  = atomicAdd(&ctrl[320 + tid], 0.f);
            float cnt = (float)(BSZ * 49);
            float mean = sum / cnt;
            float var = sq / cnt - mean * mean;
            float A = g2[tid] * rsqrtf(var + 1e-5f);
            abc2[tid] = A;
            abc2[128 + tid] = be2[tid] - mean * A;
        }
    }
}

// ---------------- light epilogue: BN2(packed)+ReLU+avgpool+FC (IPB=4) ----------------
__global__ __launch_bounds__(256) void k_final(const __bf16* __restrict__ z2,
                                               const float* __restrict__ abc2,
                                               const float* __restrict__ wfc,
                                               const float* __restrict__ bfc,
                                               float* __restrict__ out) {
    __shared__ float sbn2[256];
    __shared__ float pp[16 * 128];
    __shared__ float pooled[128];
    __shared__ float fcred[80];
    const int tid = threadIdx.x;
    sbn2[tid] = abc2[tid];
    __syncthreads();
    const int g = tid & 15, c0 = g * 8, rg = tid >> 4;
    f32x2 A2p[4], C2p[4];
#pragma unroll
    for (int p = 0; p < 4; p++) {
        A2p[p] = (f32x2){sbn2[c0 + 2 * p], sbn2[c0 + 2 * p + 1]};
        C2p[p] = (f32x2){sbn2[128 + c0 + 2 * p], sbn2[128 + c0 + 2 * p + 1]};
    }
    const f32x2 zero2 = {0.f, 0.f};
    for (int img = 0; img < 4; img++) {
        const int b = blockIdx.x * 4 + img;
        const __bf16* src = z2 + (long)b * 12544;
        f32x2 acc2[4];
#pragma unroll
        for (int p = 0; p < 4; p++) acc2[p] = zero2;
        for (int rr = rg; rr < 49; rr += 16) {
            bf16x8 v = *(const bf16x8*)&src[rr * 128 + c0];
#pragma unroll
            for (int p = 0; p < 4; p++) {
                f32x2 vf = {(float)v[2 * p], (float)v[2 * p + 1]};
                f32x2 t0 = __builtin_elementwise_fma(vf, A2p[p], C2p[p]);
                t0 = __builtin_elementwise_max(t0, zero2);
                acc2[p] = acc2[p] + t0;
            }
        }
        f32x4 lo = {acc2[0][0], acc2[0][1], acc2[1][0], acc2[1][1]};
        f32x4 hi = {acc2[2][0], acc2[2][1], acc2[3][0], acc2[3][1]};
        *(f32x4*)&pp[rg * 128 + c0]     = lo;
        *(f32x4*)&pp[rg * 128 + c0 + 4] = hi;
        __syncthreads();
        if (tid < 128) {
            float s = 0.f;
#pragma unroll
            for (int r = 0; r < 16; r++) s += pp[r * 128 + tid];
            pooled[tid] = s * (1.f / 49.f);
        }
        __syncthreads();
        if (tid < 80) {
            int o = tid >> 3, s = tid & 7;
            float a = 0.f;
#pragma unroll
            for (int j = 0; j < 16; j++) a = fmaf(pooled[s * 16 + j], wfc[o * 128 + s * 16 + j], a);
            fcred[tid] = a;
        }
        __syncthreads();
        if (tid < 10) {
            float a = bfc[tid];
#pragma unroll
            for (int s = 0; s < 8; s++) a += fcred[tid * 8 + s];
            out[(long)b * 10 + tid] = a;
        }
        __syncthreads();
    }
}

extern "C" void kernel_launch(void* const* d_in, const int* in_sizes, int n_in,
                              void* d_out, int out_size, void* d_ws, size_t ws_size,
                              hipStream_t stream) {
    const float* x   = (const float*)d_in[0];
    const float* w0  = (const float*)d_in[1];
    const float* g0  = (const float*)d_in[3];
    const float* be0 = (const float*)d_in[4];
    const float* w1  = (const float*)d_in[5];
    const float* g1  = (const float*)d_in[7];
    const float* be1 = (const float*)d_in[8];
    const float* w2  = (const float*)d_in[9];
    const float* g2  = (const float*)d_in[11];
    const float* be2 = (const float*)d_in[12];
    const float* wfc = (const float*)d_in[13];
    const float* bfc = (const float*)d_in[14];
    float* out = (float*)d_out;

    float* ctrl  = (float*)d_ws;             // 512 floats (accs + tickets)
    float* abc0  = ctrl + 512;               // 320
    float* abc1  = abc0 + 320;               // 128
    float* abc2  = abc1 + 128;               // 256
    __bf16* w1b  = (__bf16*)(abc2 + 256);    // 8192
    __bf16* w2b  = w1b + 8192;               // 32768
    __bf16* h1   = w2b + 32768;              // 8192*12544 bf16 (~205 MB); z2 aliased per-image

    hipMemsetAsync(ctrl, 0, 2048, stream);
    k_stats0<<<dim3(1024), dim3(256), 0, stream>>>(x, ctrl, w0, g0, be0, abc0, w1, w2, w1b, w2b);
    k_conv01<<<dim3(BSZ / 4), dim3(256), 0, stream>>>(x, abc0, w1b, h1, ctrl, g1, be1, abc1);
    k_conv2s<<<dim3(BSZ / 4), dim3(256), 0, stream>>>(h1, w2b, abc1, ctrl, g2, be2, abc2);
    k_final<<<dim3(BSZ / 4), dim3(256), 0, stream>>>(h1, abc2, wfc, bfc, out);
}